// Round 8
// baseline (307.514 us; speedup 1.0000x reference)
//
#include <hip/hip_runtime.h>

// A2M (LaneGCN map-agent attention) — wave-autonomous MFMA, fused pipeline.
// R8: __launch_bounds__(256,4) everywhere (VGPR=128 fits 4 waves/EU; 2x resident
// waves) + XCD-aware bijective block swizzle in edge (hi-sorted => per-XCD L2
// locality of Qc gathers). Otherwise identical to R7.

typedef __attribute__((ext_vector_type(8))) short short8v;
typedef __attribute__((ext_vector_type(4))) float f32x4;

#define NXCD 8

// ---------------- scalar helpers ----------------
__device__ __forceinline__ unsigned short f2b(float f) {
    union { float f; unsigned u; } v; v.f = f;
    return (unsigned short)((v.u + 0x7fffu + ((v.u >> 16) & 1u)) >> 16);
}
__device__ __forceinline__ unsigned pk2(float a, float b) {
    return (unsigned)f2b(a) | ((unsigned)f2b(b) << 16);
}
__device__ __forceinline__ float bflo(unsigned u) { return __uint_as_float(u << 16); }
__device__ __forceinline__ float bfhi(unsigned u) { return __uint_as_float(u & 0xffff0000u); }

union U4S8 { unsigned u[4]; short8v v; };

// ---------------- wave GEMM (2 B-sets share each W A-frag) ----------------
template<int NK>
__device__ __forceinline__ void wgemm2(const unsigned short* __restrict__ Wf,
                                       const short8v* bf0, const short8v* bf1,
                                       f32x4 (&acc0)[8], f32x4 (&acc1)[8], int l) {
#pragma unroll
    for (int mt = 0; mt < 8; mt++) {
        acc0[mt] = (f32x4){0.f, 0.f, 0.f, 0.f};
        acc1[mt] = (f32x4){0.f, 0.f, 0.f, 0.f};
#pragma unroll
        for (int kk = 0; kk < NK; kk++) {
            const short8v a = *(const short8v*)(Wf + ((size_t)(mt * NK + kk) * 64 + l) * 8);
            acc0[mt] = __builtin_amdgcn_mfma_f32_16x16x32_bf16(a, bf0[kk], acc0[mt], 0, 0, 0);
            acc1[mt] = __builtin_amdgcn_mfma_f32_16x16x32_bf16(a, bf1[kk], acc1[mt], 0, 0, 0);
        }
    }
}

// ---------------- in-register GN over 128 oc ----------------
__device__ __forceinline__ void gn_apply8(f32x4 (&acc)[8], const float* __restrict__ g,
                                          const float* __restrict__ b, int lg, bool relu) {
    float s = 0.f, s2 = 0.f;
#pragma unroll
    for (int mt = 0; mt < 8; mt++)
#pragma unroll
        for (int q = 0; q < 4; q++) { const float v = acc[mt][q]; s += v; s2 += v * v; }
    s += __shfl_xor(s, 16, 64); s2 += __shfl_xor(s2, 16, 64);
    s += __shfl_xor(s, 32, 64); s2 += __shfl_xor(s2, 32, 64);
    const float mu = s * (1.f / 128.f);
    const float rs = rsqrtf(s2 * (1.f / 128.f) - mu * mu + 1e-5f);
#pragma unroll
    for (int mt = 0; mt < 8; mt++) {
        const f32x4 g4 = *(const f32x4*)(g + mt * 16 + lg * 4);
        const f32x4 b4 = *(const f32x4*)(b + mt * 16 + lg * 4);
#pragma unroll
        for (int q = 0; q < 4; q++) {
            float y = (acc[mt][q] - mu) * rs * g4[q] + b4[q];
            acc[mt][q] = relu ? fmaxf(y, 0.f) : y;
        }
    }
}

__device__ __forceinline__ void pack_p(const f32x4 (&acc)[8], unsigned (&p)[8][2]) {
#pragma unroll
    for (int mt = 0; mt < 8; mt++) {
        p[mt][0] = pk2(acc[mt][0], acc[mt][1]);
        p[mt][1] = pk2(acc[mt][2], acc[mt][3]);
    }
}

// ---------------- per-wave LDS re-layout (oc-in-regs -> k-in-regs B-frag) ----------------
__device__ __forceinline__ void lds_put(unsigned short* wbuf, const unsigned (&p)[8][2],
                                        int lg, int col) {
#pragma unroll
    for (int mt = 0; mt < 8; mt++) {
        const unsigned long long v = (unsigned long long)p[mt][0] |
                                     ((unsigned long long)p[mt][1] << 32);
        *(unsigned long long*)((char*)wbuf + ((col * 256 + mt * 32 + lg * 8) ^ ((col & 7) << 4))) = v;
    }
}
__device__ __forceinline__ void lds_wait() {
    __asm__ volatile("s_waitcnt lgkmcnt(0)" ::: "memory");
    __builtin_amdgcn_sched_barrier(0);
}
__device__ __forceinline__ void lds_get(const unsigned short* wbuf, int lg, int col,
                                        short8v* bf) {
#pragma unroll
    for (int kk = 0; kk < 4; kk++)
        bf[kk] = *(const short8v*)((const char*)wbuf +
                 ((col * 256 + kk * 64 + lg * 16) ^ ((col & 7) << 4)));
}
__device__ __forceinline__ void relayout2(unsigned short* wbuf, int lg, int col,
                                          f32x4 (&acc0)[8], f32x4 (&acc1)[8],
                                          short8v* bf0, short8v* bf1) {
    unsigned p[8][2];
    pack_p(acc0, p); lds_put(wbuf, p, lg, col); lds_wait(); lds_get(wbuf, lg, col, bf0);
    pack_p(acc1, p); lds_put(wbuf, p, lg, col); lds_wait(); lds_get(wbuf, lg, col, bf1);
}

// ---------------- global row <-> frag helpers ----------------
__device__ __forceinline__ void load_bfrag_row(const float* __restrict__ src, int lg,
                                               short8v* bf) {
#pragma unroll
    for (int kk = 0; kk < 4; kk++) {
        const f32x4 a = *(const f32x4*)(src + kk * 32 + lg * 8);
        const f32x4 b = *(const f32x4*)(src + kk * 32 + lg * 8 + 4);
        U4S8 u;
        u.u[0] = pk2(a[0], a[1]); u.u[1] = pk2(a[2], a[3]);
        u.u[2] = pk2(b[0], b[1]); u.u[3] = pk2(b[2], b[3]);
        bf[kk] = u.v;
    }
}
__device__ __forceinline__ void store_rows(float* dst, const f32x4 (&acc)[8], int lg) {
#pragma unroll
    for (int mt = 0; mt < 8; mt++) *(f32x4*)(dst + mt * 16 + lg * 4) = acc[mt];
}
__device__ __forceinline__ void store_rows_bf16(unsigned short* dst, const f32x4 (&acc)[8], int lg) {
#pragma unroll
    for (int mt = 0; mt < 8; mt++) {
        uint2 u; u.x = pk2(acc[mt][0], acc[mt][1]); u.y = pk2(acc[mt][2], acc[mt][3]);
        *(uint2*)(dst + mt * 16 + lg * 4) = u;
    }
}
__device__ __forceinline__ void gather_issue(const unsigned short* __restrict__ Qc,
                                             const unsigned short* __restrict__ Acp,
                                             int h, int w, int lg,
                                             uint2 (&qv)[8], uint2 (&av)[8]) {
    const int hl = (h < 0) ? 0 : h;
    const unsigned short* qp = Qc  + (size_t)hl * 128 + lg * 4;
    const unsigned short* ap = Acp + (size_t)w  * 128 + lg * 4;
#pragma unroll
    for (int mt = 0; mt < 8; mt++) {
        qv[mt] = *(const uint2*)(qp + mt * 16);
        av[mt] = *(const uint2*)(ap + mt * 16);
    }
}
__device__ __forceinline__ void gather_add(f32x4 (&acc)[8], const uint2 (&qv)[8],
                                           const uint2 (&av)[8]) {
#pragma unroll
    for (int mt = 0; mt < 8; mt++) {
        acc[mt][0] += bflo(qv[mt].x) + bflo(av[mt].x);
        acc[mt][1] += bfhi(qv[mt].x) + bfhi(av[mt].x);
        acc[mt][2] += bflo(qv[mt].y) + bflo(av[mt].y);
        acc[mt][3] += bfhi(qv[mt].y) + bfhi(av[mt].y);
    }
}
__device__ __forceinline__ void build_d1(const float* __restrict__ dw1,
                                         const float* __restrict__ db1,
                                         float dx, float dy, int lg, short8v* bf) {
#pragma unroll
    for (int kk = 0; kk < 4; kk++) {
        U4S8 u;
#pragma unroll
        for (int ii = 0; ii < 4; ii++) {
            const int c0 = kk * 32 + lg * 8 + ii * 2;
            const float2 wa = *(const float2*)(dw1 + 2 * c0);
            const float2 wb = *(const float2*)(dw1 + 2 * c0 + 2);
            const float2 bb = *(const float2*)(db1 + c0);
            u.u[ii] = pk2(fmaxf(fmaf(wa.x, dx, fmaf(wa.y, dy, bb.x)), 0.f),
                          fmaxf(fmaf(wb.x, dx, fmaf(wb.y, dy, bb.y)), 0.f));
        }
        bf[kk] = u.v;
    }
}

// -------- shared node tail --------
__device__ __forceinline__ void node_tail(
    f32x4 (&acc0)[8], f32x4 (&acc1)[8],
    unsigned short* wbuf, int l, int lg, int col, int r0, int r1, int N,
    const unsigned short* __restrict__ Wagt, const unsigned short* __restrict__ Wq,
    const float* __restrict__ qg, const float* __restrict__ qb,
    const unsigned short* __restrict__ Wc1q,
    float* xB, unsigned short* Qc)
{
    short8v bf0[4], bf1[4];
    relayout2(wbuf, lg, col, acc0, acc1, bf0, bf1);
    wgemm2<4>(Wagt, bf0, bf1, acc0, acc1, l);
    if (r0 < N) store_rows(xB + (size_t)r0 * 128, acc0, lg);
    if (r1 < N) store_rows(xB + (size_t)r1 * 128, acc1, lg);
    wgemm2<4>(Wq, bf0, bf1, acc0, acc1, l);
    gn_apply8(acc0, qg, qb, lg, true);
    gn_apply8(acc1, qg, qb, lg, true);
    relayout2(wbuf, lg, col, acc0, acc1, bf0, bf1);
    wgemm2<4>(Wc1q, bf0, bf1, acc0, acc1, l);
    if (r0 < N) store_rows_bf16(Qc + (size_t)r0 * 128, acc0, lg);
    if (r1 < N) store_rows_bf16(Qc + (size_t)r1 * 128, acc1, lg);
}

// -------- agent path --------
__device__ __forceinline__ void agent_path(
    int abid, int NA, const float* __restrict__ agents,
    const unsigned short* __restrict__ Wc1a, unsigned short* Ac,
    int wid, int l, int lg, int col)
{
    const int rbase = abid * 128 + wid * 32;
    const int r0 = rbase + col, r1 = rbase + 16 + col;
    const int rc0 = min(r0, NA - 1), rc1 = min(r1, NA - 1);
    short8v bf0[4], bf1[4];
    load_bfrag_row(agents + (size_t)rc0 * 128, lg, bf0);
    load_bfrag_row(agents + (size_t)rc1 * 128, lg, bf1);
    f32x4 acc0[8], acc1[8];
    wgemm2<4>(Wc1a, bf0, bf1, acc0, acc1, l);
    if (r0 < NA) store_rows_bf16(Ac + (size_t)r0 * 128, acc0, lg);
    if (r1 < NA) store_rows_bf16(Ac + (size_t)r1 * 128, acc1, lg);
}

// ---------------- weight prep ----------------
struct PrepJob { const float* src; int dst; int ld; int kmax; int nk; };
struct PrepJobs { PrepJob j[17]; };

__global__ __launch_bounds__(64) void prep_weights(PrepJobs P, unsigned short* __restrict__ pool) {
    const PrepJob J = P.j[blockIdx.y];
    const int f = blockIdx.x;
    if (f >= 8 * J.nk) return;
    const int l = threadIdx.x;
    const int n = (f / J.nk) * 16 + (l & 15);
    const int kb = (f % J.nk) * 32 + (l >> 4) * 8;
    float v[8];
#pragma unroll
    for (int i = 0; i < 8; i++) {
        const int k = kb + i;
        v[i] = (k < J.kmax) ? J.src[(size_t)n * J.ld + k] : 0.f;
    }
    U4S8 u;
#pragma unroll
    for (int i = 0; i < 4; i++) u.u[i] = pk2(v[2 * i], v[2 * i + 1]);
    *(short8v*)(pool + J.dst + ((size_t)f * 64 + l) * 8) = u.v;
}

// ---------------- K1: meta + node_pre(0) + agent(0) ----------------
__global__ __launch_bounds__(256, 4) void meta_node(
    const int N, const int NA, const int gN,
    const float* __restrict__ feat, const float* __restrict__ turn,
    const float* __restrict__ ctrl, const float* __restrict__ inter,
    const float* __restrict__ agents,
    const unsigned short* __restrict__ Wm,
    const float* __restrict__ mg, const float* __restrict__ mb,
    const unsigned short* __restrict__ Wagt, const unsigned short* __restrict__ Wq,
    const float* __restrict__ qg, const float* __restrict__ qb,
    const unsigned short* __restrict__ Wc1q, const unsigned short* __restrict__ Wc1a,
    float* __restrict__ xA, float* __restrict__ xB,
    unsigned short* __restrict__ Qc, unsigned short* __restrict__ Ac)
{
    __shared__ unsigned short wbuf[4][2048];
    const int t = threadIdx.x, wid = t >> 6, l = t & 63, lg = l >> 4, col = l & 15;
    if (blockIdx.x >= gN) {
        agent_path(blockIdx.x - gN, NA, agents, Wc1a, Ac, wid, l, lg, col);
        return;
    }
    const int rbase = blockIdx.x * 128 + wid * 32;
    const int r0 = rbase + col, r1 = rbase + 16 + col;
    const int rc0 = min(r0, N - 1), rc1 = min(r1, N - 1);
    short8v bf0[5], bf1[5];
    load_bfrag_row(feat + (size_t)rc0 * 128, lg, bf0);
    load_bfrag_row(feat + (size_t)rc1 * 128, lg, bf1);
    {
        U4S8 u0, u1;
#pragma unroll
        for (int i = 0; i < 4; i++) { u0.u[i] = 0; u1.u[i] = 0; }
        if (lg == 0) {
            const float2 t0 = *(const float2*)(turn + (size_t)rc0 * 2);
            const float2 t1 = *(const float2*)(turn + (size_t)rc1 * 2);
            u0.u[0] = pk2(t0.x, t0.y); u0.u[1] = pk2(ctrl[rc0], inter[rc0]);
            u1.u[0] = pk2(t1.x, t1.y); u1.u[1] = pk2(ctrl[rc1], inter[rc1]);
        }
        bf0[4] = u0.v; bf1[4] = u1.v;
    }
    f32x4 acc0[8], acc1[8];
    wgemm2<5>(Wm, bf0, bf1, acc0, acc1, l);
    gn_apply8(acc0, mg, mb, lg, true);
    gn_apply8(acc1, mg, mb, lg, true);
    if (r0 < N) store_rows(xA + (size_t)r0 * 128, acc0, lg);
    if (r1 < N) store_rows(xA + (size_t)r1 * 128, acc1, lg);
    node_tail(acc0, acc1, wbuf[wid], l, lg, col, r0, r1, N,
              Wagt, Wq, qg, qb, Wc1q, xB, Qc);
}

// ---------------- post phase helper ----------------
__device__ __forceinline__ void post_load_gn(const float* xp,
                                             const float* __restrict__ ng,
                                             const float* __restrict__ nb,
                                             int lg, short8v* bf) {
    float v[4][8];
    float s = 0.f, s2 = 0.f;
#pragma unroll
    for (int kk = 0; kk < 4; kk++) {
        *(f32x4*)(v[kk])     = *(const f32x4*)(xp + kk * 32 + lg * 8);
        *(f32x4*)(v[kk] + 4) = *(const f32x4*)(xp + kk * 32 + lg * 8 + 4);
#pragma unroll
        for (int i = 0; i < 8; i++) { s += v[kk][i]; s2 += v[kk][i] * v[kk][i]; }
    }
    s += __shfl_xor(s, 16, 64); s2 += __shfl_xor(s2, 16, 64);
    s += __shfl_xor(s, 32, 64); s2 += __shfl_xor(s2, 32, 64);
    const float mu = s * (1.f / 128.f);
    const float rs = rsqrtf(s2 * (1.f / 128.f) - mu * mu + 1e-5f);
#pragma unroll
    for (int kk = 0; kk < 4; kk++) {
        float y[8];
#pragma unroll
        for (int i = 0; i < 8; i += 4) {
            const f32x4 g4 = *(const f32x4*)(ng + kk * 32 + lg * 8 + i);
            const f32x4 b4 = *(const f32x4*)(nb + kk * 32 + lg * 8 + i);
#pragma unroll
            for (int q = 0; q < 4; q++)
                y[i + q] = fmaxf((v[kk][i + q] - mu) * rs * g4[q] + b4[q], 0.f);
        }
        U4S8 u;
#pragma unroll
        for (int i = 0; i < 4; i++) u.u[i] = pk2(y[2 * i], y[2 * i + 1]);
        bf[kk] = u.v;
    }
}

// ---------------- K3: post(i) + node_pre(i+1) + agent(i+1) ----------------
__global__ __launch_bounds__(256, 4) void post_node(
    const int N, const int NA, const int gN,
    const float* __restrict__ ng, const float* __restrict__ nb,
    const unsigned short* __restrict__ Wlin,
    const float* __restrict__ lgam, const float* __restrict__ lbet,
    const float* __restrict__ agents, const unsigned short* __restrict__ Wc1a,
    const unsigned short* __restrict__ Wagt, const unsigned short* __restrict__ Wq,
    const float* __restrict__ qg, const float* __restrict__ qb,
    const unsigned short* __restrict__ Wc1q,
    float* xA, float* xB,
    unsigned short* __restrict__ Qc, unsigned short* __restrict__ Ac)
{
    __shared__ unsigned short wbuf[4][2048];
    const int t = threadIdx.x, wid = t >> 6, l = t & 63, lg = l >> 4, col = l & 15;
    if (blockIdx.x >= gN) {
        agent_path(blockIdx.x - gN, NA, agents, Wc1a, Ac, wid, l, lg, col);
        return;
    }
    const int rbase = blockIdx.x * 128 + wid * 32;
    const int r0 = rbase + col, r1 = rbase + 16 + col;
    const int rc0 = min(r0, N - 1), rc1 = min(r1, N - 1);
    short8v bf0[4], bf1[4];
    post_load_gn(xB + (size_t)rc0 * 128, ng, nb, lg, bf0);
    post_load_gn(xB + (size_t)rc1 * 128, ng, nb, lg, bf1);
    f32x4 acc0[8], acc1[8];
    wgemm2<4>(Wlin, bf0, bf1, acc0, acc1, l);
    gn_apply8(acc0, lgam, lbet, lg, false);
    gn_apply8(acc1, lgam, lbet, lg, false);
#pragma unroll
    for (int s = 0; s < 2; s++) {
        const int row = s ? rc1 : rc0;
        f32x4* ap = s ? acc1 : acc0;
        const float* rp = xA + (size_t)row * 128 + lg * 4;
#pragma unroll
        for (int mt = 0; mt < 8; mt++) {
            const f32x4 r4 = *(const f32x4*)(rp + mt * 16);
#pragma unroll
            for (int q = 0; q < 4; q++) ap[mt][q] = fmaxf(ap[mt][q] + r4[q], 0.f);
        }
    }
    if (r0 < N) store_rows(xA + (size_t)r0 * 128, acc0, lg);
    if (r1 < N) store_rows(xA + (size_t)r1 * 128, acc1, lg);
    node_tail(acc0, acc1, wbuf[wid], l, lg, col, r0, r1, N,
              Wagt, Wq, qg, qb, Wc1q, xB, Qc);
}

// ---------------- K5: final post -> d_out ----------------
__global__ __launch_bounds__(256, 4) void post_final(
    const int N,
    const float* __restrict__ xB,
    const float* __restrict__ ng, const float* __restrict__ nb,
    const unsigned short* __restrict__ Wlin,
    const float* __restrict__ lgam, const float* __restrict__ lbet,
    const float* __restrict__ res, float* __restrict__ out)
{
    const int t = threadIdx.x, wid = t >> 6, l = t & 63, lg = l >> 4, col = l & 15;
    const int rbase = blockIdx.x * 128 + wid * 32;
    const int r0 = rbase + col, r1 = rbase + 16 + col;
    const int rc0 = min(r0, N - 1), rc1 = min(r1, N - 1);
    short8v bf0[4], bf1[4];
    post_load_gn(xB + (size_t)rc0 * 128, ng, nb, lg, bf0);
    post_load_gn(xB + (size_t)rc1 * 128, ng, nb, lg, bf1);
    f32x4 acc0[8], acc1[8];
    wgemm2<4>(Wlin, bf0, bf1, acc0, acc1, l);
    gn_apply8(acc0, lgam, lbet, lg, false);
    gn_apply8(acc1, lgam, lbet, lg, false);
#pragma unroll
    for (int s = 0; s < 2; s++) {
        const int row = s ? r1 : r0;
        if (row >= N) continue;
        const f32x4* ap = s ? acc1 : acc0;
        const float* rp = res + (size_t)row * 128 + lg * 4;
        float* dp = out + (size_t)row * 128 + lg * 4;
#pragma unroll
        for (int mt = 0; mt < 8; mt++) {
            const f32x4 r4 = *(const f32x4*)(rp + mt * 16);
            f32x4 y4;
#pragma unroll
            for (int q = 0; q < 4; q++) y4[q] = fmaxf(ap[mt][q] + r4[q], 0.f);
            *(f32x4*)(dp + mt * 16) = y4;
        }
    }
}

// ---------------- edge ----------------
__device__ __forceinline__ void scatter_half(const unsigned short* buf, const int* sh,
                                             int l, int& ph, float& pA, float& pB,
                                             float* OUT) {
#pragma unroll
    for (int e = 0; e < 16; e++) {
        const int he = sh[e];
        const unsigned short uA = *(const unsigned short*)((const char*)buf +
                                  ((e * 256 + l * 2) ^ ((e & 7) << 4)));
        const unsigned short uB = *(const unsigned short*)((const char*)buf +
                                  ((e * 256 + (64 + l) * 2) ^ ((e & 7) << 4)));
        const float vA = __uint_as_float((unsigned)uA << 16);
        const float vB = __uint_as_float((unsigned)uB << 16);
        if (he == ph) { pA += vA; pB += vB; }
        else {
            if (ph >= 0) {
                atomicAdd(&OUT[(size_t)ph * 128 + l], pA);
                atomicAdd(&OUT[(size_t)ph * 128 + 64 + l], pB);
            }
            ph = he; pA = vA; pB = vB;
        }
    }
}

__global__ __launch_bounds__(256, 4) void edge_mfma(
    const int E, const int nwg,
    const int* __restrict__ hi, const int* __restrict__ wi,
    const float* __restrict__ mc, const float* __restrict__ ac,
    const float* __restrict__ dw1, const float* __restrict__ db1,
    const unsigned short* __restrict__ Wd2, const float* __restrict__ dg2, const float* __restrict__ db2,
    const unsigned short* __restrict__ Wc1d, const float* __restrict__ cg1, const float* __restrict__ cb1,
    const unsigned short* __restrict__ Wc2,
    const unsigned short* __restrict__ Qc, const unsigned short* __restrict__ Acp,
    float* __restrict__ OUT)
{
    __shared__ unsigned short wbuf[4][2048];
    __shared__ int s_h[128];
    const int t = threadIdx.x, wid = t >> 6, l = t & 63, lg = l >> 4, col = l & 15;

    // bijective XCD swizzle (m204): contiguous edge chunk per XCD -> Qc L2 locality
    int bid;
    {
        const int orig = blockIdx.x;
        const int q = nwg / NXCD, r = nwg % NXCD;
        const int xcd = orig % NXCD, i = orig / NXCD;
        bid = (xcd < r ? xcd * (q + 1) : r * (q + 1) + (xcd - r) * q) + i;
    }
    const int ebase = bid * 128 + wid * 32;

    int hv[2], wv[2];
    float dxv[2], dyv[2];
#pragma unroll
    for (int s = 0; s < 2; s++) {
        const int eidx = ebase + s * 16 + col;
        int h = -1, w = 0;
        if (eidx < E) { h = hi[eidx]; w = wi[eidx]; }
        hv[s] = h; wv[s] = w;
        if (lg == 0) s_h[wid * 32 + s * 16 + col] = h;
        const int hl = (h < 0) ? 0 : h;
        const float2 mcv = *(const float2*)(mc + 2 * (size_t)hl);
        const float2 acv = *(const float2*)(ac + 2 * (size_t)w);
        dxv[s] = mcv.x - acv.x; dyv[s] = mcv.y - acv.y;
    }

    uint2 qv0[8], av0[8], qv1[8], av1[8];
    gather_issue(Qc, Acp, hv[0], wv[0], lg, qv0, av0);
    gather_issue(Qc, Acp, hv[1], wv[1], lg, qv1, av1);

    short8v bf0[4], bf1[4];
    build_d1(dw1, db1, dxv[0], dyv[0], lg, bf0);
    build_d1(dw1, db1, dxv[1], dyv[1], lg, bf1);

    f32x4 acc0[8], acc1[8];
    unsigned p[8][2];

    wgemm2<4>(Wd2, bf0, bf1, acc0, acc1, l);
    gn_apply8(acc0, dg2, db2, lg, true);
    gn_apply8(acc1, dg2, db2, lg, true);
    relayout2(wbuf[wid], lg, col, acc0, acc1, bf0, bf1);

    wgemm2<4>(Wc1d, bf0, bf1, acc0, acc1, l);
    gather_add(acc0, qv0, av0);
    gather_add(acc1, qv1, av1);
    gn_apply8(acc0, cg1, cb1, lg, true);
    gn_apply8(acc1, cg1, cb1, lg, true);
    relayout2(wbuf[wid], lg, col, acc0, acc1, bf0, bf1);

    wgemm2<4>(Wc2, bf0, bf1, acc0, acc1, l);

    float pA = 0.f, pB = 0.f; int ph = -1;
    pack_p(acc0, p); lds_put(wbuf[wid], p, lg, col); lds_wait();
    scatter_half(wbuf[wid], s_h + wid * 32, l, ph, pA, pB, OUT);
    pack_p(acc1, p); lds_put(wbuf[wid], p, lg, col); lds_wait();
    scatter_half(wbuf[wid], s_h + wid * 32 + 16, l, ph, pA, pB, OUT);
    if (ph >= 0) {
        atomicAdd(&OUT[(size_t)ph * 128 + l], pA);
        atomicAdd(&OUT[(size_t)ph * 128 + 64 + l], pB);
    }
}

extern "C" void kernel_launch(void* const* d_in, const int* in_sizes, int n_in,
                              void* d_out, int out_size, void* d_ws, size_t ws_size,
                              hipStream_t stream)
{
    const float* feat    = (const float*)d_in[0];
    const float* turn    = (const float*)d_in[1];
    const float* ctrl    = (const float*)d_in[2];
    const float* inter   = (const float*)d_in[3];
    const float* agents  = (const float*)d_in[4];
    const float* mc      = (const float*)d_in[5];
    const float* ac      = (const float*)d_in[6];
    const float* meta_w  = (const float*)d_in[7];
    const float* meta_g  = (const float*)d_in[8];
    const float* meta_b  = (const float*)d_in[9];
    const float* dist_w1 = (const float*)d_in[10];
    const float* dist_b1 = (const float*)d_in[11];
    const float* dist_w2 = (const float*)d_in[12];
    const float* dist_g2 = (const float*)d_in[13];
    const float* dist_b2 = (const float*)d_in[14];
    const float* query_w = (const float*)d_in[15];
    const float* query_g = (const float*)d_in[16];
    const float* query_b = (const float*)d_in[17];
    const float* ctx_w1  = (const float*)d_in[18];
    const float* ctx_g1  = (const float*)d_in[19];
    const float* ctx_b1  = (const float*)d_in[20];
    const float* ctx_w2  = (const float*)d_in[21];
    const float* agt_w   = (const float*)d_in[22];
    const float* norm_g  = (const float*)d_in[23];
    const float* norm_b  = (const float*)d_in[24];
    const float* lin_w   = (const float*)d_in[25];
    const float* lin_g   = (const float*)d_in[26];
    const float* lin_b   = (const float*)d_in[27];
    const int*   hi      = (const int*)d_in[28];
    const int*   wi      = (const int*)d_in[29];

    const int E  = in_sizes[28];
    const int N  = in_sizes[0] / 128;   // 64000
    const int NA = in_sizes[4] / 128;   // 2048

    float* xA = (float*)d_ws;
    float* xB = xA + (size_t)N * 128;
    unsigned short* pool = (unsigned short*)(xB + (size_t)N * 128);

    const int FR128  = 8 * 4 * 64 * 8;
    const int FRMETA = 8 * 5 * 64 * 8;
    const int POOL_ELEMS = FRMETA + 16 * FR128;

    unsigned short* Ac = pool + POOL_ELEMS;
    unsigned short* Qc = (unsigned short*)d_out;

    PrepJobs P;
    P.j[0] = { meta_w, 0, 132, 132, 5 };
    for (int i = 0; i < 2; i++) {
        const int b = FRMETA + i * 8 * FR128;
        P.j[1 + i * 8 + 0] = { query_w + (size_t)i * 16384, b + 0 * FR128, 128, 128, 4 };
        P.j[1 + i * 8 + 1] = { agt_w   + (size_t)i * 16384, b + 1 * FR128, 128, 128, 4 };
        P.j[1 + i * 8 + 2] = { dist_w2 + (size_t)i * 16384, b + 2 * FR128, 128, 128, 4 };
        P.j[1 + i * 8 + 3] = { ctx_w1  + (size_t)i * 49152,       b + 3 * FR128, 384, 128, 4 };
        P.j[1 + i * 8 + 4] = { ctx_w1  + (size_t)i * 49152 + 128, b + 4 * FR128, 384, 128, 4 };
        P.j[1 + i * 8 + 5] = { ctx_w2  + (size_t)i * 16384, b + 5 * FR128, 128, 128, 4 };
        P.j[1 + i * 8 + 6] = { lin_w   + (size_t)i * 16384, b + 6 * FR128, 128, 128, 4 };
        P.j[1 + i * 8 + 7] = { ctx_w1  + (size_t)i * 49152 + 256, b + 7 * FR128, 384, 128, 4 };
    }
    prep_weights<<<dim3(40, 17), 64, 0, stream>>>(P, pool);

    const int gN = (N + 127) / 128;
    const int gA = (NA + 127) / 128;
    const int gE = (E + 127) / 128;

    const unsigned short* W0 = pool + FRMETA;
    const unsigned short* W1 = pool + FRMETA + 8 * FR128;

    meta_node<<<gN + gA, 256, 0, stream>>>(
        N, NA, gN, feat, turn, ctrl, inter, agents,
        pool, meta_g, meta_b,
        W0 + 1 * FR128, W0 + 0 * FR128, query_g, query_b,
        W0 + 4 * FR128, W0 + 7 * FR128,
        xA, xB, Qc, Ac);

    edge_mfma<<<gE, 256, 0, stream>>>(
        E, gE, hi, wi, mc, ac,
        dist_w1, dist_b1,
        W0 + 2 * FR128, dist_g2, dist_b2,
        W0 + 3 * FR128, ctx_g1, ctx_b1,
        W0 + 5 * FR128, Qc, Ac, xB);

    post_node<<<gN + gA, 256, 0, stream>>>(
        N, NA, gN,
        norm_g, norm_b, W0 + 6 * FR128, lin_g, lin_b,
        agents, W1 + 7 * FR128,
        W1 + 1 * FR128, W1 + 0 * FR128, query_g + 128, query_b + 128,
        W1 + 4 * FR128,
        xA, xB, Qc, Ac);

    edge_mfma<<<gE, 256, 0, stream>>>(
        E, gE, hi, wi, mc, ac,
        dist_w1 + 256, dist_b1 + 128,
        W1 + 2 * FR128, dist_g2 + 128, dist_b2 + 128,
        W1 + 3 * FR128, ctx_g1 + 128, ctx_b1 + 128,
        W1 + 5 * FR128, Qc, Ac, xB);

    post_final<<<gN, 256, 0, stream>>>(
        N, xB, norm_g + 128, norm_b + 128,
        W1 + 6 * FR128, lin_g + 128, lin_b + 128, xA, (float*)d_out);
}

// Round 9
// 251.861 us; speedup vs baseline: 1.2210x; 1.2210x over previous
//
#include <hip/hip_runtime.h>

// A2M (LaneGCN map-agent attention) — wave-autonomous MFMA, fused pipeline.
// R9: single B-set per wave (16 rows/edges) to halve live VGPRs; compiler can
// pipeline W-frag loads (R7 was vmcnt(0)-serialized at ~500cy/load). Launch
// bounds (256,2) — non-binding, no spills. XCD swizzle kept in edge.
// ws: xA, xB (N*128 f32), bf16 weight pool, Ac bf16. Qc bf16 in d_out scratch.

typedef __attribute__((ext_vector_type(8))) short short8v;
typedef __attribute__((ext_vector_type(4))) float f32x4;

#define NXCD 8

// ---------------- scalar helpers ----------------
__device__ __forceinline__ unsigned short f2b(float f) {
    union { float f; unsigned u; } v; v.f = f;
    return (unsigned short)((v.u + 0x7fffu + ((v.u >> 16) & 1u)) >> 16);
}
__device__ __forceinline__ unsigned pk2(float a, float b) {
    return (unsigned)f2b(a) | ((unsigned)f2b(b) << 16);
}
__device__ __forceinline__ float bflo(unsigned u) { return __uint_as_float(u << 16); }
__device__ __forceinline__ float bfhi(unsigned u) { return __uint_as_float(u & 0xffff0000u); }

union U4S8 { unsigned u[4]; short8v v; };

// ---------------- wave GEMM, single B-set ----------------
// W A-frag: lane&15 = oc row, k=(lane>>4)*8+i. x B-frag: lane&15 = col (row/edge).
// D: col = lane&15, oc = mt*16 + (lane>>4)*4 + q.
template<int NK>
__device__ __forceinline__ void wgemm1(const unsigned short* __restrict__ Wf,
                                       const short8v* bf, f32x4 (&acc)[8], int l) {
#pragma unroll
    for (int mt = 0; mt < 8; mt++) {
        acc[mt] = (f32x4){0.f, 0.f, 0.f, 0.f};
#pragma unroll
        for (int kk = 0; kk < NK; kk++) {
            const short8v a = *(const short8v*)(Wf + ((size_t)(mt * NK + kk) * 64 + l) * 8);
            acc[mt] = __builtin_amdgcn_mfma_f32_16x16x32_bf16(a, bf[kk], acc[mt], 0, 0, 0);
        }
    }
}

// ---------------- in-register GN over 128 oc ----------------
__device__ __forceinline__ void gn_apply8(f32x4 (&acc)[8], const float* __restrict__ g,
                                          const float* __restrict__ b, int lg, bool relu) {
    float s = 0.f, s2 = 0.f;
#pragma unroll
    for (int mt = 0; mt < 8; mt++)
#pragma unroll
        for (int q = 0; q < 4; q++) { const float v = acc[mt][q]; s += v; s2 += v * v; }
    s += __shfl_xor(s, 16, 64); s2 += __shfl_xor(s2, 16, 64);
    s += __shfl_xor(s, 32, 64); s2 += __shfl_xor(s2, 32, 64);
    const float mu = s * (1.f / 128.f);
    const float rs = rsqrtf(s2 * (1.f / 128.f) - mu * mu + 1e-5f);
#pragma unroll
    for (int mt = 0; mt < 8; mt++) {
        const f32x4 g4 = *(const f32x4*)(g + mt * 16 + lg * 4);
        const f32x4 b4 = *(const f32x4*)(b + mt * 16 + lg * 4);
#pragma unroll
        for (int q = 0; q < 4; q++) {
            float y = (acc[mt][q] - mu) * rs * g4[q] + b4[q];
            acc[mt][q] = relu ? fmaxf(y, 0.f) : y;
        }
    }
}

__device__ __forceinline__ void pack_p(const f32x4 (&acc)[8], unsigned (&p)[8][2]) {
#pragma unroll
    for (int mt = 0; mt < 8; mt++) {
        p[mt][0] = pk2(acc[mt][0], acc[mt][1]);
        p[mt][1] = pk2(acc[mt][2], acc[mt][3]);
    }
}

// ---------------- per-wave LDS re-layout ----------------
__device__ __forceinline__ void lds_put(unsigned short* wbuf, const unsigned (&p)[8][2],
                                        int lg, int col) {
#pragma unroll
    for (int mt = 0; mt < 8; mt++) {
        const unsigned long long v = (unsigned long long)p[mt][0] |
                                     ((unsigned long long)p[mt][1] << 32);
        *(unsigned long long*)((char*)wbuf + ((col * 256 + mt * 32 + lg * 8) ^ ((col & 7) << 4))) = v;
    }
}
__device__ __forceinline__ void lds_wait() {
    __asm__ volatile("s_waitcnt lgkmcnt(0)" ::: "memory");
    __builtin_amdgcn_sched_barrier(0);
}
__device__ __forceinline__ void lds_get(const unsigned short* wbuf, int lg, int col,
                                        short8v* bf) {
#pragma unroll
    for (int kk = 0; kk < 4; kk++)
        bf[kk] = *(const short8v*)((const char*)wbuf +
                 ((col * 256 + kk * 64 + lg * 16) ^ ((col & 7) << 4)));
}
__device__ __forceinline__ void relayout1(unsigned short* wbuf, int lg, int col,
                                          f32x4 (&acc)[8], short8v* bf) {
    unsigned p[8][2];
    pack_p(acc, p); lds_put(wbuf, p, lg, col); lds_wait(); lds_get(wbuf, lg, col, bf);
}

// ---------------- global row <-> frag helpers ----------------
__device__ __forceinline__ void load_bfrag_row(const float* __restrict__ src, int lg,
                                               short8v* bf) {
#pragma unroll
    for (int kk = 0; kk < 4; kk++) {
        const f32x4 a = *(const f32x4*)(src + kk * 32 + lg * 8);
        const f32x4 b = *(const f32x4*)(src + kk * 32 + lg * 8 + 4);
        U4S8 u;
        u.u[0] = pk2(a[0], a[1]); u.u[1] = pk2(a[2], a[3]);
        u.u[2] = pk2(b[0], b[1]); u.u[3] = pk2(b[2], b[3]);
        bf[kk] = u.v;
    }
}
__device__ __forceinline__ void store_rows(float* dst, const f32x4 (&acc)[8], int lg) {
#pragma unroll
    for (int mt = 0; mt < 8; mt++) *(f32x4*)(dst + mt * 16 + lg * 4) = acc[mt];
}
__device__ __forceinline__ void store_rows_bf16(unsigned short* dst, const f32x4 (&acc)[8], int lg) {
#pragma unroll
    for (int mt = 0; mt < 8; mt++) {
        uint2 u; u.x = pk2(acc[mt][0], acc[mt][1]); u.y = pk2(acc[mt][2], acc[mt][3]);
        *(uint2*)(dst + mt * 16 + lg * 4) = u;
    }
}
__device__ __forceinline__ void gather_issue(const unsigned short* __restrict__ Qc,
                                             const unsigned short* __restrict__ Acp,
                                             int h, int w, int lg,
                                             uint2 (&qv)[8], uint2 (&av)[8]) {
    const int hl = (h < 0) ? 0 : h;
    const unsigned short* qp = Qc  + (size_t)hl * 128 + lg * 4;
    const unsigned short* ap = Acp + (size_t)w  * 128 + lg * 4;
#pragma unroll
    for (int mt = 0; mt < 8; mt++) {
        qv[mt] = *(const uint2*)(qp + mt * 16);
        av[mt] = *(const uint2*)(ap + mt * 16);
    }
}
__device__ __forceinline__ void gather_add(f32x4 (&acc)[8], const uint2 (&qv)[8],
                                           const uint2 (&av)[8]) {
#pragma unroll
    for (int mt = 0; mt < 8; mt++) {
        acc[mt][0] += bflo(qv[mt].x) + bflo(av[mt].x);
        acc[mt][1] += bfhi(qv[mt].x) + bfhi(av[mt].x);
        acc[mt][2] += bflo(qv[mt].y) + bflo(av[mt].y);
        acc[mt][3] += bfhi(qv[mt].y) + bfhi(av[mt].y);
    }
}
__device__ __forceinline__ void build_d1(const float* __restrict__ dw1,
                                         const float* __restrict__ db1,
                                         float dx, float dy, int lg, short8v* bf) {
#pragma unroll
    for (int kk = 0; kk < 4; kk++) {
        U4S8 u;
#pragma unroll
        for (int ii = 0; ii < 4; ii++) {
            const int c0 = kk * 32 + lg * 8 + ii * 2;
            const float2 wa = *(const float2*)(dw1 + 2 * c0);
            const float2 wb = *(const float2*)(dw1 + 2 * c0 + 2);
            const float2 bb = *(const float2*)(db1 + c0);
            u.u[ii] = pk2(fmaxf(fmaf(wa.x, dx, fmaf(wa.y, dy, bb.x)), 0.f),
                          fmaxf(fmaf(wb.x, dx, fmaf(wb.y, dy, bb.y)), 0.f));
        }
        bf[kk] = u.v;
    }
}

// -------- shared node tail (single set) --------
__device__ __forceinline__ void node_tail(
    f32x4 (&acc)[8],
    unsigned short* wbuf, int l, int lg, int col, int r, int N,
    const unsigned short* __restrict__ Wagt, const unsigned short* __restrict__ Wq,
    const float* __restrict__ qg, const float* __restrict__ qb,
    const unsigned short* __restrict__ Wc1q,
    float* xB, unsigned short* Qc)
{
    short8v bf[4];
    relayout1(wbuf, lg, col, acc, bf);
    wgemm1<4>(Wagt, bf, acc, l);
    if (r < N) store_rows(xB + (size_t)r * 128, acc, lg);
    wgemm1<4>(Wq, bf, acc, l);
    gn_apply8(acc, qg, qb, lg, true);
    relayout1(wbuf, lg, col, acc, bf);
    wgemm1<4>(Wc1q, bf, acc, l);
    if (r < N) store_rows_bf16(Qc + (size_t)r * 128, acc, lg);
}

// -------- agent path --------
__device__ __forceinline__ void agent_path(
    int abid, int NA, const float* __restrict__ agents,
    const unsigned short* __restrict__ Wc1a, unsigned short* Ac,
    int wid, int l, int lg, int col)
{
    const int r = abid * 64 + wid * 16 + col;
    const int rc = min(r, NA - 1);
    short8v bf[4];
    load_bfrag_row(agents + (size_t)rc * 128, lg, bf);
    f32x4 acc[8];
    wgemm1<4>(Wc1a, bf, acc, l);
    if (r < NA) store_rows_bf16(Ac + (size_t)r * 128, acc, lg);
}

// ---------------- weight prep ----------------
struct PrepJob { const float* src; int dst; int ld; int kmax; int nk; };
struct PrepJobs { PrepJob j[17]; };

__global__ __launch_bounds__(64) void prep_weights(PrepJobs P, unsigned short* __restrict__ pool) {
    const PrepJob J = P.j[blockIdx.y];
    const int f = blockIdx.x;
    if (f >= 8 * J.nk) return;
    const int l = threadIdx.x;
    const int n = (f / J.nk) * 16 + (l & 15);
    const int kb = (f % J.nk) * 32 + (l >> 4) * 8;
    float v[8];
#pragma unroll
    for (int i = 0; i < 8; i++) {
        const int k = kb + i;
        v[i] = (k < J.kmax) ? J.src[(size_t)n * J.ld + k] : 0.f;
    }
    U4S8 u;
#pragma unroll
    for (int i = 0; i < 4; i++) u.u[i] = pk2(v[2 * i], v[2 * i + 1]);
    *(short8v*)(pool + J.dst + ((size_t)f * 64 + l) * 8) = u.v;
}

// ---------------- K1: meta + node_pre(0) + agent(0) ----------------
__global__ __launch_bounds__(256, 2) void meta_node(
    const int N, const int NA, const int gN,
    const float* __restrict__ feat, const float* __restrict__ turn,
    const float* __restrict__ ctrl, const float* __restrict__ inter,
    const float* __restrict__ agents,
    const unsigned short* __restrict__ Wm,
    const float* __restrict__ mg, const float* __restrict__ mb,
    const unsigned short* __restrict__ Wagt, const unsigned short* __restrict__ Wq,
    const float* __restrict__ qg, const float* __restrict__ qb,
    const unsigned short* __restrict__ Wc1q, const unsigned short* __restrict__ Wc1a,
    float* __restrict__ xA, float* __restrict__ xB,
    unsigned short* __restrict__ Qc, unsigned short* __restrict__ Ac)
{
    __shared__ unsigned short wbuf[4][2048];
    const int t = threadIdx.x, wid = t >> 6, l = t & 63, lg = l >> 4, col = l & 15;
    if (blockIdx.x >= gN) {
        agent_path(blockIdx.x - gN, NA, agents, Wc1a, Ac, wid, l, lg, col);
        return;
    }
    const int r = blockIdx.x * 64 + wid * 16 + col;
    const int rc = min(r, N - 1);
    short8v bf[5];
    load_bfrag_row(feat + (size_t)rc * 128, lg, bf);
    {
        U4S8 u; u.u[0] = 0; u.u[1] = 0; u.u[2] = 0; u.u[3] = 0;
        if (lg == 0) {
            const float2 tv = *(const float2*)(turn + (size_t)rc * 2);
            u.u[0] = pk2(tv.x, tv.y);
            u.u[1] = pk2(ctrl[rc], inter[rc]);
        }
        bf[4] = u.v;
    }
    f32x4 acc[8];
    wgemm1<5>(Wm, bf, acc, l);
    gn_apply8(acc, mg, mb, lg, true);
    if (r < N) store_rows(xA + (size_t)r * 128, acc, lg);
    node_tail(acc, wbuf[wid], l, lg, col, r, N, Wagt, Wq, qg, qb, Wc1q, xB, Qc);
}

// ---------------- post phase helper ----------------
__device__ __forceinline__ void post_load_gn(const float* xp,
                                             const float* __restrict__ ng,
                                             const float* __restrict__ nb,
                                             int lg, short8v* bf) {
    float v[4][8];
    float s = 0.f, s2 = 0.f;
#pragma unroll
    for (int kk = 0; kk < 4; kk++) {
        *(f32x4*)(v[kk])     = *(const f32x4*)(xp + kk * 32 + lg * 8);
        *(f32x4*)(v[kk] + 4) = *(const f32x4*)(xp + kk * 32 + lg * 8 + 4);
#pragma unroll
        for (int i = 0; i < 8; i++) { s += v[kk][i]; s2 += v[kk][i] * v[kk][i]; }
    }
    s += __shfl_xor(s, 16, 64); s2 += __shfl_xor(s2, 16, 64);
    s += __shfl_xor(s, 32, 64); s2 += __shfl_xor(s2, 32, 64);
    const float mu = s * (1.f / 128.f);
    const float rs = rsqrtf(s2 * (1.f / 128.f) - mu * mu + 1e-5f);
#pragma unroll
    for (int kk = 0; kk < 4; kk++) {
        float y[8];
#pragma unroll
        for (int i = 0; i < 8; i += 4) {
            const f32x4 g4 = *(const f32x4*)(ng + kk * 32 + lg * 8 + i);
            const f32x4 b4 = *(const f32x4*)(nb + kk * 32 + lg * 8 + i);
#pragma unroll
            for (int q = 0; q < 4; q++)
                y[i + q] = fmaxf((v[kk][i + q] - mu) * rs * g4[q] + b4[q], 0.f);
        }
        U4S8 u;
#pragma unroll
        for (int i = 0; i < 4; i++) u.u[i] = pk2(y[2 * i], y[2 * i + 1]);
        bf[kk] = u.v;
    }
}

// ---------------- K3: post(i) + node_pre(i+1) + agent(i+1) ----------------
__global__ __launch_bounds__(256, 2) void post_node(
    const int N, const int NA, const int gN,
    const float* __restrict__ ng, const float* __restrict__ nb,
    const unsigned short* __restrict__ Wlin,
    const float* __restrict__ lgam, const float* __restrict__ lbet,
    const float* __restrict__ agents, const unsigned short* __restrict__ Wc1a,
    const unsigned short* __restrict__ Wagt, const unsigned short* __restrict__ Wq,
    const float* __restrict__ qg, const float* __restrict__ qb,
    const unsigned short* __restrict__ Wc1q,
    float* xA, float* xB,
    unsigned short* __restrict__ Qc, unsigned short* __restrict__ Ac)
{
    __shared__ unsigned short wbuf[4][2048];
    const int t = threadIdx.x, wid = t >> 6, l = t & 63, lg = l >> 4, col = l & 15;
    if (blockIdx.x >= gN) {
        agent_path(blockIdx.x - gN, NA, agents, Wc1a, Ac, wid, l, lg, col);
        return;
    }
    const int r = blockIdx.x * 64 + wid * 16 + col;
    const int rc = min(r, N - 1);
    short8v bf[4];
    post_load_gn(xB + (size_t)rc * 128, ng, nb, lg, bf);
    f32x4 acc[8];
    wgemm1<4>(Wlin, bf, acc, l);
    gn_apply8(acc, lgam, lbet, lg, false);
    {
        const float* rp = xA + (size_t)rc * 128 + lg * 4;
#pragma unroll
        for (int mt = 0; mt < 8; mt++) {
            const f32x4 r4 = *(const f32x4*)(rp + mt * 16);
#pragma unroll
            for (int q = 0; q < 4; q++) acc[mt][q] = fmaxf(acc[mt][q] + r4[q], 0.f);
        }
    }
    if (r < N) store_rows(xA + (size_t)r * 128, acc, lg);
    node_tail(acc, wbuf[wid], l, lg, col, r, N, Wagt, Wq, qg, qb, Wc1q, xB, Qc);
}

// ---------------- K5: final post -> d_out ----------------
__global__ __launch_bounds__(256, 2) void post_final(
    const int N,
    const float* __restrict__ xB,
    const float* __restrict__ ng, const float* __restrict__ nb,
    const unsigned short* __restrict__ Wlin,
    const float* __restrict__ lgam, const float* __restrict__ lbet,
    const float* __restrict__ res, float* __restrict__ out)
{
    const int t = threadIdx.x, wid = t >> 6, l = t & 63, lg = l >> 4, col = l & 15;
    const int r = blockIdx.x * 64 + wid * 16 + col;
    const int rc = min(r, N - 1);
    short8v bf[4];
    post_load_gn(xB + (size_t)rc * 128, ng, nb, lg, bf);
    f32x4 acc[8];
    wgemm1<4>(Wlin, bf, acc, l);
    gn_apply8(acc, lgam, lbet, lg, false);
    if (r < N) {
        const float* rp = res + (size_t)r * 128 + lg * 4;
        float* dp = out + (size_t)r * 128 + lg * 4;
#pragma unroll
        for (int mt = 0; mt < 8; mt++) {
            const f32x4 r4 = *(const f32x4*)(rp + mt * 16);
            f32x4 y4;
#pragma unroll
            for (int q = 0; q < 4; q++) y4[q] = fmaxf(acc[mt][q] + r4[q], 0.f);
            *(f32x4*)(dp + mt * 16) = y4;
        }
    }
}

// ---------------- edge ----------------
__global__ __launch_bounds__(256, 2) void edge_mfma(
    const int E, const int nwg,
    const int* __restrict__ hi, const int* __restrict__ wi,
    const float* __restrict__ mc, const float* __restrict__ ac,
    const float* __restrict__ dw1, const float* __restrict__ db1,
    const unsigned short* __restrict__ Wd2, const float* __restrict__ dg2, const float* __restrict__ db2,
    const unsigned short* __restrict__ Wc1d, const float* __restrict__ cg1, const float* __restrict__ cb1,
    const unsigned short* __restrict__ Wc2,
    const unsigned short* __restrict__ Qc, const unsigned short* __restrict__ Acp,
    float* __restrict__ OUT)
{
    __shared__ unsigned short wbuf[4][2048];
    __shared__ int s_h[64];
    const int t = threadIdx.x, wid = t >> 6, l = t & 63, lg = l >> 4, col = l & 15;

    // bijective XCD swizzle (m204): contiguous edge chunk per XCD -> Qc L2 locality
    int bid;
    {
        const int orig = blockIdx.x;
        const int q = nwg / NXCD, r = nwg % NXCD;
        const int xcd = orig % NXCD, i = orig / NXCD;
        bid = (xcd < r ? xcd * (q + 1) : r * (q + 1) + (xcd - r) * q) + i;
    }
    const int eidx = bid * 64 + wid * 16 + col;

    int h = -1, w = 0;
    if (eidx < E) { h = hi[eidx]; w = wi[eidx]; }
    if (lg == 0) s_h[wid * 16 + col] = h;
    const int hl = (h < 0) ? 0 : h;
    const float2 mcv = *(const float2*)(mc + 2 * (size_t)hl);
    const float2 acv = *(const float2*)(ac + 2 * (size_t)w);
    const float dx = mcv.x - acv.x, dy = mcv.y - acv.y;

    // issue gathers early (32 VGPRs, consumed after GEMM2)
    uint2 qv[8], av[8];
    gather_issue(Qc, Acp, h, w, lg, qv, av);

    short8v bf[4];
    build_d1(dw1, db1, dx, dy, lg, bf);

    f32x4 acc[8];
    unsigned p[8][2];

    wgemm1<4>(Wd2, bf, acc, l);
    gn_apply8(acc, dg2, db2, lg, true);
    relayout1(wbuf[wid], lg, col, acc, bf);

    wgemm1<4>(Wc1d, bf, acc, l);
    gather_add(acc, qv, av);
    gn_apply8(acc, cg1, cb1, lg, true);
    relayout1(wbuf[wid], lg, col, acc, bf);

    wgemm1<4>(Wc2, bf, acc, l);
    pack_p(acc, p); lds_put(wbuf[wid], p, lg, col); lds_wait();

    // scatter: 2 channel passes (l, 64+l), run-combined over 16 sorted-hi edges
#pragma unroll
    for (int pass = 0; pass < 2; pass++) {
        const int c = pass * 64 + l;
        float pend = 0.f; int ph = -1;
#pragma unroll
        for (int e = 0; e < 16; e++) {
            const int he = s_h[wid * 16 + e];
            const unsigned short uv = *(const unsigned short*)((const char*)wbuf[wid] +
                                      ((e * 256 + c * 2) ^ ((e & 7) << 4)));
            const float v = __uint_as_float((unsigned)uv << 16);
            if (he == ph) pend += v;
            else {
                if (ph >= 0) atomicAdd(&OUT[(size_t)ph * 128 + c], pend);
                ph = he; pend = v;
            }
        }
        if (ph >= 0) atomicAdd(&OUT[(size_t)ph * 128 + c], pend);
    }
}

extern "C" void kernel_launch(void* const* d_in, const int* in_sizes, int n_in,
                              void* d_out, int out_size, void* d_ws, size_t ws_size,
                              hipStream_t stream)
{
    const float* feat    = (const float*)d_in[0];
    const float* turn    = (const float*)d_in[1];
    const float* ctrl    = (const float*)d_in[2];
    const float* inter   = (const float*)d_in[3];
    const float* agents  = (const float*)d_in[4];
    const float* mc      = (const float*)d_in[5];
    const float* ac      = (const float*)d_in[6];
    const float* meta_w  = (const float*)d_in[7];
    const float* meta_g  = (const float*)d_in[8];
    const float* meta_b  = (const float*)d_in[9];
    const float* dist_w1 = (const float*)d_in[10];
    const float* dist_b1 = (const float*)d_in[11];
    const float* dist_w2 = (const float*)d_in[12];
    const float* dist_g2 = (const float*)d_in[13];
    const float* dist_b2 = (const float*)d_in[14];
    const float* query_w = (const float*)d_in[15];
    const float* query_g = (const float*)d_in[16];
    const float* query_b = (const float*)d_in[17];
    const float* ctx_w1  = (const float*)d_in[18];
    const float* ctx_g1  = (const float*)d_in[19];
    const float* ctx_b1  = (const float*)d_in[20];
    const float* ctx_w2  = (const float*)d_in[21];
    const float* agt_w   = (const float*)d_in[22];
    const float* norm_g  = (const float*)d_in[23];
    const float* norm_b  = (const float*)d_in[24];
    const float* lin_w   = (const float*)d_in[25];
    const float* lin_g   = (const float*)d_in[26];
    const float* lin_b   = (const float*)d_in[27];
    const int*   hi      = (const int*)d_in[28];
    const int*   wi      = (const int*)d_in[29];

    const int E  = in_sizes[28];
    const int N  = in_sizes[0] / 128;   // 64000
    const int NA = in_sizes[4] / 128;   // 2048

    float* xA = (float*)d_ws;
    float* xB = xA + (size_t)N * 128;
    unsigned short* pool = (unsigned short*)(xB + (size_t)N * 128);

    const int FR128  = 8 * 4 * 64 * 8;
    const int FRMETA = 8 * 5 * 64 * 8;
    const int POOL_ELEMS = FRMETA + 16 * FR128;

    unsigned short* Ac = pool + POOL_ELEMS;
    unsigned short* Qc = (unsigned short*)d_out;

    PrepJobs P;
    P.j[0] = { meta_w, 0, 132, 132, 5 };
    for (int i = 0; i < 2; i++) {
        const int b = FRMETA + i * 8 * FR128;
        P.j[1 + i * 8 + 0] = { query_w + (size_t)i * 16384, b + 0 * FR128, 128, 128, 4 };
        P.j[1 + i * 8 + 1] = { agt_w   + (size_t)i * 16384, b + 1 * FR128, 128, 128, 4 };
        P.j[1 + i * 8 + 2] = { dist_w2 + (size_t)i * 16384, b + 2 * FR128, 128, 128, 4 };
        P.j[1 + i * 8 + 3] = { ctx_w1  + (size_t)i * 49152,       b + 3 * FR128, 384, 128, 4 };
        P.j[1 + i * 8 + 4] = { ctx_w1  + (size_t)i * 49152 + 128, b + 4 * FR128, 384, 128, 4 };
        P.j[1 + i * 8 + 5] = { ctx_w2  + (size_t)i * 16384, b + 5 * FR128, 128, 128, 4 };
        P.j[1 + i * 8 + 6] = { lin_w   + (size_t)i * 16384, b + 6 * FR128, 128, 128, 4 };
        P.j[1 + i * 8 + 7] = { ctx_w1  + (size_t)i * 49152 + 256, b + 7 * FR128, 384, 128, 4 };
    }
    prep_weights<<<dim3(40, 17), 64, 0, stream>>>(P, pool);

    const int gN = (N + 63) / 64;
    const int gA = (NA + 63) / 64;
    const int gE = (E + 63) / 64;

    const unsigned short* W0 = pool + FRMETA;
    const unsigned short* W1 = pool + FRMETA + 8 * FR128;

    meta_node<<<gN + gA, 256, 0, stream>>>(
        N, NA, gN, feat, turn, ctrl, inter, agents,
        pool, meta_g, meta_b,
        W0 + 1 * FR128, W0 + 0 * FR128, query_g, query_b,
        W0 + 4 * FR128, W0 + 7 * FR128,
        xA, xB, Qc, Ac);

    edge_mfma<<<gE, 256, 0, stream>>>(
        E, gE, hi, wi, mc, ac,
        dist_w1, dist_b1,
        W0 + 2 * FR128, dist_g2, dist_b2,
        W0 + 3 * FR128, ctx_g1, ctx_b1,
        W0 + 5 * FR128, Qc, Ac, xB);

    post_node<<<gN + gA, 256, 0, stream>>>(
        N, NA, gN,
        norm_g, norm_b, W0 + 6 * FR128, lin_g, lin_b,
        agents, W1 + 7 * FR128,
        W1 + 1 * FR128, W1 + 0 * FR128, query_g + 128, query_b + 128,
        W1 + 4 * FR128,
        xA, xB, Qc, Ac);

    edge_mfma<<<gE, 256, 0, stream>>>(
        E, gE, hi, wi, mc, ac,
        dist_w1 + 256, dist_b1 + 128,
        W1 + 2 * FR128, dist_g2 + 128, dist_b2 + 128,
        W1 + 3 * FR128, ctx_g1 + 128, ctx_b1 + 128,
        W1 + 5 * FR128, Qc, Ac, xB);

    post_final<<<gN, 256, 0, stream>>>(
        N, xB, norm_g + 128, norm_b + 128,
        W1 + 6 * FR128, lin_g + 128, lin_b + 128, xA, (float*)d_out);
}

// Round 10
// 202.142 us; speedup vs baseline: 1.5213x; 1.2460x over previous
//
#include <hip/hip_runtime.h>

// A2M (LaneGCN map-agent attention) — MFMA + LDS-staged weights.
// R10: per-block weight staging into LDS (reg-staged, load-early/write-late),
// GEMMs read W via ds_read_b128 (lgkmcnt); gathers stay on vmcnt and remain
// in flight across bar_lds() (lgkmcnt-only barrier). Single B-set per wave.
// ws: xA, xB (N*128 f32), bf16 weight pool, Ac bf16. Qc bf16 in d_out scratch.

typedef __attribute__((ext_vector_type(8))) short short8v;
typedef __attribute__((ext_vector_type(4))) float f32x4;

#define NXCD 8

// ---------------- scalar helpers ----------------
__device__ __forceinline__ unsigned short f2b(float f) {
    union { float f; unsigned u; } v; v.f = f;
    return (unsigned short)((v.u + 0x7fffu + ((v.u >> 16) & 1u)) >> 16);
}
__device__ __forceinline__ unsigned pk2(float a, float b) {
    return (unsigned)f2b(a) | ((unsigned)f2b(b) << 16);
}
__device__ __forceinline__ float bflo(unsigned u) { return __uint_as_float(u << 16); }
__device__ __forceinline__ float bfhi(unsigned u) { return __uint_as_float(u & 0xffff0000u); }

union U4S8 { unsigned u[4]; short8v v; };

// ---------------- LDS barrier that does NOT drain vmcnt ----------------
__device__ __forceinline__ void bar_lds() {
    __builtin_amdgcn_sched_barrier(0);
    asm volatile("s_waitcnt lgkmcnt(0)" ::: "memory");
    __builtin_amdgcn_s_barrier();
    __builtin_amdgcn_sched_barrier(0);
}

// ---------------- weight staging: global -> regs (early) -> LDS (late) ----------------
template<int NV>
__device__ __forceinline__ void sload(short8v (&v)[NV], const unsigned short* __restrict__ src,
                                      int t) {
#pragma unroll
    for (int i = 0; i < NV; i++) v[i] = *(const short8v*)(src + (size_t)i * 2048 + t * 8);
}
template<int NV>
__device__ __forceinline__ void swrite(unsigned short* dst, const short8v (&v)[NV], int t) {
#pragma unroll
    for (int i = 0; i < NV; i++) *(short8v*)(dst + i * 2048 + t * 8) = v[i];
}

// ---------------- wave GEMM from LDS weights ----------------
// W A-frag (LDS): lane&15 = oc row, k=(lane>>4)*8+i. x B-frag: lane&15 = col.
// D: col = lane&15, oc = mt*16 + (lane>>4)*4 + q.
template<int NK>
__device__ __forceinline__ void wgemm_lds(const unsigned short* Wlds,
                                          const short8v* bf, f32x4 (&acc)[8], int l) {
#pragma unroll
    for (int mt = 0; mt < 8; mt++) {
        acc[mt] = (f32x4){0.f, 0.f, 0.f, 0.f};
#pragma unroll
        for (int kk = 0; kk < NK; kk++) {
            const short8v a = *(const short8v*)(Wlds + ((mt * NK + kk) * 64 + l) * 8);
            acc[mt] = __builtin_amdgcn_mfma_f32_16x16x32_bf16(a, bf[kk], acc[mt], 0, 0, 0);
        }
    }
}

// ---------------- in-register GN over 128 oc ----------------
__device__ __forceinline__ void gn_apply8(f32x4 (&acc)[8], const float* __restrict__ g,
                                          const float* __restrict__ b, int lg, bool relu) {
    float s = 0.f, s2 = 0.f;
#pragma unroll
    for (int mt = 0; mt < 8; mt++)
#pragma unroll
        for (int q = 0; q < 4; q++) { const float v = acc[mt][q]; s += v; s2 += v * v; }
    s += __shfl_xor(s, 16, 64); s2 += __shfl_xor(s2, 16, 64);
    s += __shfl_xor(s, 32, 64); s2 += __shfl_xor(s2, 32, 64);
    const float mu = s * (1.f / 128.f);
    const float rs = rsqrtf(s2 * (1.f / 128.f) - mu * mu + 1e-5f);
#pragma unroll
    for (int mt = 0; mt < 8; mt++) {
        const f32x4 g4 = *(const f32x4*)(g + mt * 16 + lg * 4);
        const f32x4 b4 = *(const f32x4*)(b + mt * 16 + lg * 4);
#pragma unroll
        for (int q = 0; q < 4; q++) {
            float y = (acc[mt][q] - mu) * rs * g4[q] + b4[q];
            acc[mt][q] = relu ? fmaxf(y, 0.f) : y;
        }
    }
}

__device__ __forceinline__ void pack_p(const f32x4 (&acc)[8], unsigned (&p)[8][2]) {
#pragma unroll
    for (int mt = 0; mt < 8; mt++) {
        p[mt][0] = pk2(acc[mt][0], acc[mt][1]);
        p[mt][1] = pk2(acc[mt][2], acc[mt][3]);
    }
}

// ---------------- per-wave LDS re-layout (oc-in-regs -> k-in-regs B-frag) ----------------
__device__ __forceinline__ void lds_put(unsigned short* wbuf, const unsigned (&p)[8][2],
                                        int lg, int col) {
#pragma unroll
    for (int mt = 0; mt < 8; mt++) {
        const unsigned long long v = (unsigned long long)p[mt][0] |
                                     ((unsigned long long)p[mt][1] << 32);
        *(unsigned long long*)((char*)wbuf + ((col * 256 + mt * 32 + lg * 8) ^ ((col & 7) << 4))) = v;
    }
}
__device__ __forceinline__ void lds_wait() {
    asm volatile("s_waitcnt lgkmcnt(0)" ::: "memory");
    __builtin_amdgcn_sched_barrier(0);
}
__device__ __forceinline__ void lds_get(const unsigned short* wbuf, int lg, int col,
                                        short8v* bf) {
#pragma unroll
    for (int kk = 0; kk < 4; kk++)
        bf[kk] = *(const short8v*)((const char*)wbuf +
                 ((col * 256 + kk * 64 + lg * 16) ^ ((col & 7) << 4)));
}
__device__ __forceinline__ void relayout1(unsigned short* wbuf, int lg, int col,
                                          f32x4 (&acc)[8], short8v* bf) {
    unsigned p[8][2];
    pack_p(acc, p); lds_put(wbuf, p, lg, col); lds_wait(); lds_get(wbuf, lg, col, bf);
}

// ---------------- global row <-> frag helpers ----------------
__device__ __forceinline__ void load_bfrag_row(const float* __restrict__ src, int lg,
                                               short8v* bf) {
#pragma unroll
    for (int kk = 0; kk < 4; kk++) {
        const f32x4 a = *(const f32x4*)(src + kk * 32 + lg * 8);
        const f32x4 b = *(const f32x4*)(src + kk * 32 + lg * 8 + 4);
        U4S8 u;
        u.u[0] = pk2(a[0], a[1]); u.u[1] = pk2(a[2], a[3]);
        u.u[2] = pk2(b[0], b[1]); u.u[3] = pk2(b[2], b[3]);
        bf[kk] = u.v;
    }
}
__device__ __forceinline__ void store_rows(float* dst, const f32x4 (&acc)[8], int lg) {
#pragma unroll
    for (int mt = 0; mt < 8; mt++) *(f32x4*)(dst + mt * 16 + lg * 4) = acc[mt];
}
__device__ __forceinline__ void store_rows_bf16(unsigned short* dst, const f32x4 (&acc)[8], int lg) {
#pragma unroll
    for (int mt = 0; mt < 8; mt++) {
        uint2 u; u.x = pk2(acc[mt][0], acc[mt][1]); u.y = pk2(acc[mt][2], acc[mt][3]);
        *(uint2*)(dst + mt * 16 + lg * 4) = u;
    }
}
__device__ __forceinline__ void gather_issue(const unsigned short* __restrict__ Qc,
                                             const unsigned short* __restrict__ Acp,
                                             int h, int w, int lg,
                                             uint2 (&qv)[8], uint2 (&av)[8]) {
    const int hl = (h < 0) ? 0 : h;
    const unsigned short* qp = Qc  + (size_t)hl * 128 + lg * 4;
    const unsigned short* ap = Acp + (size_t)w  * 128 + lg * 4;
#pragma unroll
    for (int mt = 0; mt < 8; mt++) {
        qv[mt] = *(const uint2*)(qp + mt * 16);
        av[mt] = *(const uint2*)(ap + mt * 16);
    }
}
__device__ __forceinline__ void gather_add(f32x4 (&acc)[8], const uint2 (&qv)[8],
                                           const uint2 (&av)[8]) {
#pragma unroll
    for (int mt = 0; mt < 8; mt++) {
        acc[mt][0] += bflo(qv[mt].x) + bflo(av[mt].x);
        acc[mt][1] += bfhi(qv[mt].x) + bfhi(av[mt].x);
        acc[mt][2] += bflo(qv[mt].y) + bflo(av[mt].y);
        acc[mt][3] += bfhi(qv[mt].y) + bfhi(av[mt].y);
    }
}
__device__ __forceinline__ void build_d1(const float* __restrict__ dw1,
                                         const float* __restrict__ db1,
                                         float dx, float dy, int lg, short8v* bf) {
#pragma unroll
    for (int kk = 0; kk < 4; kk++) {
        U4S8 u;
#pragma unroll
        for (int ii = 0; ii < 4; ii++) {
            const int c0 = kk * 32 + lg * 8 + ii * 2;
            const float2 wa = *(const float2*)(dw1 + 2 * c0);
            const float2 wb = *(const float2*)(dw1 + 2 * c0 + 2);
            const float2 bb = *(const float2*)(db1 + c0);
            u.u[ii] = pk2(fmaxf(fmaf(wa.x, dx, fmaf(wa.y, dy, bb.x)), 0.f),
                          fmaxf(fmaf(wb.x, dx, fmaf(wb.y, dy, bb.y)), 0.f));
        }
        bf[kk] = u.v;
    }
}

// ---------------- weight prep ----------------
struct PrepJob { const float* src; int dst; int ld; int kmax; int nk; };
struct PrepJobs { PrepJob j[17]; };

__global__ __launch_bounds__(64) void prep_weights(PrepJobs P, unsigned short* __restrict__ pool) {
    const PrepJob J = P.j[blockIdx.y];
    const int f = blockIdx.x;
    if (f >= 8 * J.nk) return;
    const int l = threadIdx.x;
    const int n = (f / J.nk) * 16 + (l & 15);
    const int kb = (f % J.nk) * 32 + (l >> 4) * 8;
    float v[8];
#pragma unroll
    for (int i = 0; i < 8; i++) {
        const int k = kb + i;
        v[i] = (k < J.kmax) ? J.src[(size_t)n * J.ld + k] : 0.f;
    }
    U4S8 u;
#pragma unroll
    for (int i = 0; i < 4; i++) u.u[i] = pk2(v[2 * i], v[2 * i + 1]);
    *(short8v*)(pool + J.dst + ((size_t)f * 64 + l) * 8) = u.v;
}

// -------- agent branch body (shared by K1/K3) --------
__device__ __forceinline__ void agent_path(
    unsigned short* Wlds, int abid, int NA, const float* __restrict__ agents,
    const unsigned short* __restrict__ Wc1a, unsigned short* Ac,
    int t, int wid, int l, int lg, int col)
{
    short8v sv[8];
    sload<8>(sv, Wc1a, t);
    const int r = abid * 64 + wid * 16 + col;
    const int rc = min(r, NA - 1);
    short8v bf[4];
    load_bfrag_row(agents + (size_t)rc * 128, lg, bf);
    swrite<8>(Wlds, sv, t);
    bar_lds();
    f32x4 acc[8];
    wgemm_lds<4>(Wlds, bf, acc, l);
    if (r < NA) store_rows_bf16(Ac + (size_t)r * 128, acc, lg);
}

// ---------------- K1: meta + node_pre(0) + agent(0) ----------------
__global__ __launch_bounds__(256, 2) void meta_node(
    const int N, const int NA, const int gN,
    const float* __restrict__ feat, const float* __restrict__ turn,
    const float* __restrict__ ctrl, const float* __restrict__ inter,
    const float* __restrict__ agents,
    const unsigned short* __restrict__ Wm,
    const float* __restrict__ mg, const float* __restrict__ mb,
    const unsigned short* __restrict__ Wagt, const unsigned short* __restrict__ Wq,
    const float* __restrict__ qg, const float* __restrict__ qb,
    const unsigned short* __restrict__ Wc1q, const unsigned short* __restrict__ Wc1a,
    float* __restrict__ xA, float* __restrict__ xB,
    unsigned short* __restrict__ Qc, unsigned short* __restrict__ Ac)
{
    __shared__ unsigned short Wlds[20480];
    __shared__ unsigned short wbuf[4][2048];
    const int t = threadIdx.x, wid = t >> 6, l = t & 63, lg = l >> 4, col = l & 15;
    if (blockIdx.x >= gN) {
        agent_path(Wlds, blockIdx.x - gN, NA, agents, Wc1a, Ac, t, wid, l, lg, col);
        return;
    }
    const int r = blockIdx.x * 64 + wid * 16 + col;
    const int rc = min(r, N - 1);

    short8v s10[10];
    sload<10>(s10, Wm, t);                    // stage meta W early
    short8v bf[5];
    load_bfrag_row(feat + (size_t)rc * 128, lg, bf);
    {
        U4S8 u; u.u[0] = 0; u.u[1] = 0; u.u[2] = 0; u.u[3] = 0;
        if (lg == 0) {
            const float2 tv = *(const float2*)(turn + (size_t)rc * 2);
            u.u[0] = pk2(tv.x, tv.y);
            u.u[1] = pk2(ctrl[rc], inter[rc]);
        }
        bf[4] = u.v;
    }
    swrite<10>(Wlds, s10, t);
    bar_lds();

    short8v s8[8];
    sload<8>(s8, Wagt, t);                    // next W in flight under GEMM1
    f32x4 acc[8];
    wgemm_lds<5>(Wlds, bf, acc, l);
    gn_apply8(acc, mg, mb, lg, true);
    if (r < N) store_rows(xA + (size_t)r * 128, acc, lg);
    short8v bx[4];
    relayout1(wbuf[wid], lg, col, acc, bx);
    bar_lds();                                // all waves done reading Wm
    swrite<8>(Wlds, s8, t);
    bar_lds();

    sload<8>(s8, Wq, t);
    wgemm_lds<4>(Wlds, bx, acc, l);
    if (r < N) store_rows(xB + (size_t)r * 128, acc, lg);
    bar_lds();
    swrite<8>(Wlds, s8, t);
    bar_lds();

    sload<8>(s8, Wc1q, t);
    wgemm_lds<4>(Wlds, bx, acc, l);
    gn_apply8(acc, qg, qb, lg, true);
    relayout1(wbuf[wid], lg, col, acc, bx);
    bar_lds();
    swrite<8>(Wlds, s8, t);
    bar_lds();

    wgemm_lds<4>(Wlds, bx, acc, l);
    if (r < N) store_rows_bf16(Qc + (size_t)r * 128, acc, lg);
}

// ---------------- post phase helper ----------------
__device__ __forceinline__ void post_load_gn(const float* xp,
                                             const float* __restrict__ ng,
                                             const float* __restrict__ nb,
                                             int lg, short8v* bf) {
    float v[4][8];
    float s = 0.f, s2 = 0.f;
#pragma unroll
    for (int kk = 0; kk < 4; kk++) {
        *(f32x4*)(v[kk])     = *(const f32x4*)(xp + kk * 32 + lg * 8);
        *(f32x4*)(v[kk] + 4) = *(const f32x4*)(xp + kk * 32 + lg * 8 + 4);
#pragma unroll
        for (int i = 0; i < 8; i++) { s += v[kk][i]; s2 += v[kk][i] * v[kk][i]; }
    }
    s += __shfl_xor(s, 16, 64); s2 += __shfl_xor(s2, 16, 64);
    s += __shfl_xor(s, 32, 64); s2 += __shfl_xor(s2, 32, 64);
    const float mu = s * (1.f / 128.f);
    const float rs = rsqrtf(s2 * (1.f / 128.f) - mu * mu + 1e-5f);
#pragma unroll
    for (int kk = 0; kk < 4; kk++) {
        float y[8];
#pragma unroll
        for (int i = 0; i < 8; i += 4) {
            const f32x4 g4 = *(const f32x4*)(ng + kk * 32 + lg * 8 + i);
            const f32x4 b4 = *(const f32x4*)(nb + kk * 32 + lg * 8 + i);
#pragma unroll
            for (int q = 0; q < 4; q++)
                y[i + q] = fmaxf((v[kk][i + q] - mu) * rs * g4[q] + b4[q], 0.f);
        }
        U4S8 u;
#pragma unroll
        for (int i = 0; i < 4; i++) u.u[i] = pk2(y[2 * i], y[2 * i + 1]);
        bf[kk] = u.v;
    }
}

// ---------------- K3: post(i) + node_pre(i+1) + agent(i+1) ----------------
__global__ __launch_bounds__(256, 2) void post_node(
    const int N, const int NA, const int gN,
    const float* __restrict__ ng, const float* __restrict__ nb,
    const unsigned short* __restrict__ Wlin,
    const float* __restrict__ lgam, const float* __restrict__ lbet,
    const float* __restrict__ agents, const unsigned short* __restrict__ Wc1a,
    const unsigned short* __restrict__ Wagt, const unsigned short* __restrict__ Wq,
    const float* __restrict__ qg, const float* __restrict__ qb,
    const unsigned short* __restrict__ Wc1q,
    float* xA, float* xB,
    unsigned short* __restrict__ Qc, unsigned short* __restrict__ Ac)
{
    __shared__ unsigned short Wlds[16384];
    __shared__ unsigned short wbuf[4][2048];
    const int t = threadIdx.x, wid = t >> 6, l = t & 63, lg = l >> 4, col = l & 15;
    if (blockIdx.x >= gN) {
        agent_path(Wlds, blockIdx.x - gN, NA, agents, Wc1a, Ac, t, wid, l, lg, col);
        return;
    }
    const int r = blockIdx.x * 64 + wid * 16 + col;
    const int rc = min(r, N - 1);

    short8v s8[8];
    sload<8>(s8, Wlin, t);
    short8v bf[4];
    post_load_gn(xB + (size_t)rc * 128, ng, nb, lg, bf);
    swrite<8>(Wlds, s8, t);
    bar_lds();

    sload<8>(s8, Wagt, t);
    f32x4 acc[8];
    wgemm_lds<4>(Wlds, bf, acc, l);
    gn_apply8(acc, lgam, lbet, lg, false);
    {
        const float* rp = xA + (size_t)rc * 128 + lg * 4;
#pragma unroll
        for (int mt = 0; mt < 8; mt++) {
            const f32x4 r4 = *(const f32x4*)(rp + mt * 16);
#pragma unroll
            for (int q = 0; q < 4; q++) acc[mt][q] = fmaxf(acc[mt][q] + r4[q], 0.f);
        }
    }
    if (r < N) store_rows(xA + (size_t)r * 128, acc, lg);
    short8v bx[4];
    relayout1(wbuf[wid], lg, col, acc, bx);
    bar_lds();
    swrite<8>(Wlds, s8, t);
    bar_lds();

    sload<8>(s8, Wq, t);
    wgemm_lds<4>(Wlds, bx, acc, l);
    if (r < N) store_rows(xB + (size_t)r * 128, acc, lg);
    bar_lds();
    swrite<8>(Wlds, s8, t);
    bar_lds();

    sload<8>(s8, Wc1q, t);
    wgemm_lds<4>(Wlds, bx, acc, l);
    gn_apply8(acc, qg, qb, lg, true);
    relayout1(wbuf[wid], lg, col, acc, bx);
    bar_lds();
    swrite<8>(Wlds, s8, t);
    bar_lds();

    wgemm_lds<4>(Wlds, bx, acc, l);
    if (r < N) store_rows_bf16(Qc + (size_t)r * 128, acc, lg);
}

// ---------------- K5: final post -> d_out ----------------
__global__ __launch_bounds__(256, 2) void post_final(
    const int N,
    const float* __restrict__ xB,
    const float* __restrict__ ng, const float* __restrict__ nb,
    const unsigned short* __restrict__ Wlin,
    const float* __restrict__ lgam, const float* __restrict__ lbet,
    const float* __restrict__ res, float* __restrict__ out)
{
    __shared__ unsigned short Wlds[16384];
    const int t = threadIdx.x, wid = t >> 6, l = t & 63, lg = l >> 4, col = l & 15;
    const int r = blockIdx.x * 64 + wid * 16 + col;
    const int rc = min(r, N - 1);
    short8v s8[8];
    sload<8>(s8, Wlin, t);
    short8v bf[4];
    post_load_gn(xB + (size_t)rc * 128, ng, nb, lg, bf);
    swrite<8>(Wlds, s8, t);
    bar_lds();
    f32x4 acc[8];
    wgemm_lds<4>(Wlds, bf, acc, l);
    gn_apply8(acc, lgam, lbet, lg, false);
    if (r < N) {
        const float* rp = res + (size_t)r * 128 + lg * 4;
        float* dp = out + (size_t)r * 128 + lg * 4;
#pragma unroll
        for (int mt = 0; mt < 8; mt++) {
            const f32x4 r4 = *(const f32x4*)(rp + mt * 16);
            f32x4 y4;
#pragma unroll
            for (int q = 0; q < 4; q++) y4[q] = fmaxf(acc[mt][q] + r4[q], 0.f);
            *(f32x4*)(dp + mt * 16) = y4;
        }
    }
}

// ---------------- edge ----------------
__global__ __launch_bounds__(256, 2) void edge_mfma(
    const int E, const int nwg,
    const int* __restrict__ hi, const int* __restrict__ wi,
    const float* __restrict__ mc, const float* __restrict__ ac,
    const float* __restrict__ dw1, const float* __restrict__ db1,
    const unsigned short* __restrict__ Wd2, const float* __restrict__ dg2, const float* __restrict__ db2,
    const unsigned short* __restrict__ Wc1d, const float* __restrict__ cg1, const float* __restrict__ cb1,
    const unsigned short* __restrict__ Wc2,
    const unsigned short* __restrict__ Qc, const unsigned short* __restrict__ Acp,
    float* __restrict__ OUT)
{
    __shared__ unsigned short Wlds[16384];
    __shared__ unsigned short wbuf[4][2048];
    __shared__ int s_h[64];
    const int t = threadIdx.x, wid = t >> 6, l = t & 63, lg = l >> 4, col = l & 15;

    int bid;
    {
        const int orig = blockIdx.x;
        const int q = nwg / NXCD, r = nwg % NXCD;
        const int xcd = orig % NXCD, i = orig / NXCD;
        bid = (xcd < r ? xcd * (q + 1) : r * (q + 1) + (xcd - r) * q) + i;
    }
    const int eidx = bid * 64 + wid * 16 + col;

    short8v s8[8];
    sload<8>(s8, Wd2, t);                     // W1 in flight under setup

    int h = -1, w = 0;
    if (eidx < E) { h = hi[eidx]; w = wi[eidx]; }
    if (lg == 0) s_h[wid * 16 + col] = h;
    const int hl = (h < 0) ? 0 : h;
    const float2 mcv = *(const float2*)(mc + 2 * (size_t)hl);
    const float2 acv = *(const float2*)(ac + 2 * (size_t)w);
    const float dx = mcv.x - acv.x, dy = mcv.y - acv.y;

    // gathers issued now; stay on vmcnt across bar_lds, consumed after GEMM2
    uint2 qv[8], av[8];
    gather_issue(Qc, Acp, h, w, lg, qv, av);

    short8v bf[4];
    build_d1(dw1, db1, dx, dy, lg, bf);

    swrite<8>(Wlds, s8, t);
    bar_lds();

    sload<8>(s8, Wc1d, t);                    // W2 in flight under GEMM1
    f32x4 acc[8];
    wgemm_lds<4>(Wlds, bf, acc, l);
    gn_apply8(acc, dg2, db2, lg, true);
    relayout1(wbuf[wid], lg, col, acc, bf);
    bar_lds();
    swrite<8>(Wlds, s8, t);
    bar_lds();

    sload<8>(s8, Wc2, t);                     // W3 in flight under GEMM2
    wgemm_lds<4>(Wlds, bf, acc, l);
    gather_add(acc, qv, av);
    gn_apply8(acc, cg1, cb1, lg, true);
    relayout1(wbuf[wid], lg, col, acc, bf);
    bar_lds();
    swrite<8>(Wlds, s8, t);
    bar_lds();

    wgemm_lds<4>(Wlds, bf, acc, l);
    unsigned p[8][2];
    pack_p(acc, p); lds_put(wbuf[wid], p, lg, col); lds_wait();

    // scatter: 2 channel passes (l, 64+l), run-combined over 16 sorted-hi edges
#pragma unroll
    for (int pass = 0; pass < 2; pass++) {
        const int c = pass * 64 + l;
        float pend = 0.f; int ph = -1;
#pragma unroll
        for (int e = 0; e < 16; e++) {
            const int he = s_h[wid * 16 + e];
            const unsigned short uv = *(const unsigned short*)((const char*)wbuf[wid] +
                                      ((e * 256 + c * 2) ^ ((e & 7) << 4)));
            const float v = __uint_as_float((unsigned)uv << 16);
            if (he == ph) pend += v;
            else {
                if (ph >= 0) atomicAdd(&OUT[(size_t)ph * 128 + c], pend);
                ph = he; pend = v;
            }
        }
        if (ph >= 0) atomicAdd(&OUT[(size_t)ph * 128 + c], pend);
    }
}

extern "C" void kernel_launch(void* const* d_in, const int* in_sizes, int n_in,
                              void* d_out, int out_size, void* d_ws, size_t ws_size,
                              hipStream_t stream)
{
    const float* feat    = (const float*)d_in[0];
    const float* turn    = (const float*)d_in[1];
    const float* ctrl    = (const float*)d_in[2];
    const float* inter   = (const float*)d_in[3];
    const float* agents  = (const float*)d_in[4];
    const float* mc      = (const float*)d_in[5];
    const float* ac      = (const float*)d_in[6];
    const float* meta_w  = (const float*)d_in[7];
    const float* meta_g  = (const float*)d_in[8];
    const float* meta_b  = (const float*)d_in[9];
    const float* dist_w1 = (const float*)d_in[10];
    const float* dist_b1 = (const float*)d_in[11];
    const float* dist_w2 = (const float*)d_in[12];
    const float* dist_g2 = (const float*)d_in[13];
    const float* dist_b2 = (const float*)d_in[14];
    const float* query_w = (const float*)d_in[15];
    const float* query_g = (const float*)d_in[16];
    const float* query_b = (const float*)d_in[17];
    const float* ctx_w1  = (const float*)d_in[18];
    const float* ctx_g1  = (const float*)d_in[19];
    const float* ctx_b1  = (const float*)d_in[20];
    const float* ctx_w2  = (const float*)d_in[21];
    const float* agt_w   = (const float*)d_in[22];
    const float* norm_g  = (const float*)d_in[23];
    const float* norm_b  = (const float*)d_in[24];
    const float* lin_w   = (const float*)d_in[25];
    const float* lin_g   = (const float*)d_in[26];
    const float* lin_b   = (const float*)d_in[27];
    const int*   hi      = (const int*)d_in[28];
    const int*   wi      = (const int*)d_in[29];

    const int E  = in_sizes[28];
    const int N  = in_sizes[0] / 128;   // 64000
    const int NA = in_sizes[4] / 128;   // 2048

    float* xA = (float*)d_ws;
    float* xB = xA + (size_t)N * 128;
    unsigned short* pool = (unsigned short*)(xB + (size_t)N * 128);

    const int FR128  = 8 * 4 * 64 * 8;
    const int FRMETA = 8 * 5 * 64 * 8;
    const int POOL_ELEMS = FRMETA + 16 * FR128;

    unsigned short* Ac = pool + POOL_ELEMS;
    unsigned short* Qc = (unsigned short*)d_out;

    PrepJobs P;
    P.j[0] = { meta_w, 0, 132, 132, 5 };
    for (int i = 0; i < 2; i++) {
        const int b = FRMETA + i * 8 * FR128;
        P.j[1 + i * 8 + 0] = { query_w + (size_t)i * 16384, b + 0 * FR128, 128, 128, 4 };
        P.j[1 + i * 8 + 1] = { agt_w   + (size_t)i * 16384, b + 1 * FR128, 128, 128, 4 };
        P.j[1 + i * 8 + 2] = { dist_w2 + (size_t)i * 16384, b + 2 * FR128, 128, 128, 4 };
        P.j[1 + i * 8 + 3] = { ctx_w1  + (size_t)i * 49152,       b + 3 * FR128, 384, 128, 4 };
        P.j[1 + i * 8 + 4] = { ctx_w1  + (size_t)i * 49152 + 128, b + 4 * FR128, 384, 128, 4 };
        P.j[1 + i * 8 + 5] = { ctx_w2  + (size_t)i * 16384, b + 5 * FR128, 128, 128, 4 };
        P.j[1 + i * 8 + 6] = { lin_w   + (size_t)i * 16384, b + 6 * FR128, 128, 128, 4 };
        P.j[1 + i * 8 + 7] = { ctx_w1  + (size_t)i * 49152 + 256, b + 7 * FR128, 384, 128, 4 };
    }
    prep_weights<<<dim3(40, 17), 64, 0, stream>>>(P, pool);

    const int gN = (N + 63) / 64;
    const int gA = (NA + 63) / 64;
    const int gE = (E + 63) / 64;

    const unsigned short* W0 = pool + FRMETA;
    const unsigned short* W1 = pool + FRMETA + 8 * FR128;

    meta_node<<<gN + gA, 256, 0, stream>>>(
        N, NA, gN, feat, turn, ctrl, inter, agents,
        pool, meta_g, meta_b,
        W0 + 1 * FR128, W0 + 0 * FR128, query_g, query_b,
        W0 + 4 * FR128, W0 + 7 * FR128,
        xA, xB, Qc, Ac);

    edge_mfma<<<gE, 256, 0, stream>>>(
        E, gE, hi, wi, mc, ac,
        dist_w1, dist_b1,
        W0 + 2 * FR128, dist_g2, dist_b2,
        W0 + 3 * FR128, ctx_g1, ctx_b1,
        W0 + 5 * FR128, Qc, Ac, xB);

    post_node<<<gN + gA, 256, 0, stream>>>(
        N, NA, gN,
        norm_g, norm_b, W0 + 6 * FR128, lin_g, lin_b,
        agents, W1 + 7 * FR128,
        W1 + 1 * FR128, W1 + 0 * FR128, query_g + 128, query_b + 128,
        W1 + 4 * FR128,
        xA, xB, Qc, Ac);

    edge_mfma<<<gE, 256, 0, stream>>>(
        E, gE, hi, wi, mc, ac,
        dist_w1 + 256, dist_b1 + 128,
        W1 + 2 * FR128, dist_g2 + 128, dist_b2 + 128,
        W1 + 3 * FR128, ctx_g1 + 128, ctx_b1 + 128,
        W1 + 5 * FR128, Qc, Ac, xB);

    post_final<<<gN, 256, 0, stream>>>(
        N, xB, norm_g + 128, norm_b + 128,
        W1 + 6 * FR128, lin_g + 128, lin_b + 128, xA, (float*)d_out);
}